// Round 9
// baseline (323.118 us; speedup 1.0000x reference)
//
#include <hip/hip_runtime.h>
#include <math.h>
#include <stdint.h>

#define B_ 8
#define C_ 256
#define HW_ 4096
#define NPIX 32768
#define NELEM (B_*C_*HW_)   // 8388608

typedef __attribute__((ext_vector_type(8))) short short8;
typedef __attribute__((ext_vector_type(4))) float f32x4;

__device__ __forceinline__ unsigned short f2bf(float f) {
    union { float f; uint32_t u; } v; v.f = f;
    uint32_t r = v.u + 0x7FFFu + ((v.u >> 16) & 1u);
    return (unsigned short)(r >> 16);
}
__device__ __forceinline__ float b2f(unsigned short h) {
    union { uint32_t u; float f; } v; v.u = ((uint32_t)h) << 16; return v.f;
}
__device__ __forceinline__ float silu_f(float v) { return v / (1.f + __expf(-v)); }

// DPP-based lane combine (VALU pipe, not LDS pipe)
template<int CTRL>
__device__ __forceinline__ float dpp_add(float v) {
    int s = __builtin_amdgcn_update_dpp(0, __float_as_int(v), CTRL, 0xF, 0xF, true);
    return v + __int_as_float(s);
}

// ---------------- K0: weight conversion + p_w transpose ---------------------
__global__ __launch_bounds__(256) void prep_kernel(
    const float* __restrict__ akw, const float* __restrict__ l1w,
    const float* __restrict__ cvw, const float* __restrict__ pw,
    unsigned short* __restrict__ wak, unsigned short* __restrict__ wl1,
    unsigned short* __restrict__ wcv, float* __restrict__ pwt)
{
    int gid = blockIdx.x * 256 + threadIdx.x;      // grid=1352
    if (gid < 196608) {
        unsigned co = (unsigned)gid / 768u;
        unsigned kp = (unsigned)gid - co * 768u;   // k'' = n*256+ci
        unsigned n = kp >> 8, ci = kp & 255;
        wak[gid] = f2bf(akw[co * 768 + ci * 3 + n]);
    }
    else if (gid < 262144) { int g = gid - 196608; wl1[g] = f2bf(l1w[g]); }
    else if (gid < 327680) { int g = gid - 262144; wcv[g] = f2bf(cvw[g]); }
    else if (gid < 346112) {
        int idx = gid - 327680;
        int ci = idx / 72, r = idx - ci * 72;
        int tt = r / 12, t9 = r - tt * 12;
        pwt[idx] = (t9 < 9) ? pw[tt * 2304 + ci * 9 + t9] : 0.f;
    }
}

// ---------------- K0b: x CHW -> HWC transpose (XCD-swizzled) ----------------
__global__ __launch_bounds__(256) void transpose_kernel(
    const float* __restrict__ x, float* __restrict__ xt)
{
    int blk = blockIdx.x;            // 1024
    int b = blk & 7;
    int rest = blk >> 3;             // 0..127
    int half = rest & 1, i = rest >> 1;
    int bi = b * 64 + i;
    int tid = threadIdx.x;
    __shared__ float tile[64 * 132];

    {
        int ci_l = tid >> 6, jj = tid & 63;
        const float* ip = x + ((size_t)b * C_ + half * 128 + ci_l) * HW_ + i * 64 + jj;
        #pragma unroll 4
        for (int it = 0; it < 32; ++it)
            tile[jj * 132 + ci_l + it * 4] = ip[(size_t)it * 4 * HW_];
    }
    __syncthreads();
    {
        int j = tid >> 2, q = tid & 3;
        float* op = xt + ((size_t)(bi * 64 + j)) * 256 + half * 128 + q * 32;
        #pragma unroll
        for (int f = 0; f < 8; ++f)
            *(float4*)(op + f * 4) = *(const float4*)&tile[j * 132 + q * 32 + f * 4];
    }
}

// ---------------- K1a: offset conv stage 1 (v4: DPP reduction) --------------
// Staging mapping unchanged. Compute mapping: ci bits 0-3 on lane bits 0-3,
// ci bit4 = wave bit0; jg = lane bits 4-5 | (wave bit1)<<2.
// 16-ci reduce in VALU DPP (xor1,xor2,ror4,ror8); cross-wave via 768-float LDS.
__global__ __launch_bounds__(256) void offset_s1_kernel(
    const float* __restrict__ x, const float* __restrict__ pwt,
    float* __restrict__ part)          // [bi*8+g][6][64]
{
    int blk = blockIdx.x;              // 4096
    int b = blk & 7;
    int rest = blk >> 3;               // 0..511
    int g = rest & 7, i = rest >> 3;
    int bi = b * 64 + i;
    int tid = threadIdx.x;
    int lane = tid & 63, wave = tid >> 6;

    __shared__ float tile[6600];       // x tile; reused for cross-wave combine

    // ---- stage x tile (unchanged mapping) ----
    {
        int cs = tid >> 3, r8 = tid & 7;
        const float* xp = x + ((size_t)b * C_ + g * 32 + cs) * HW_;
        #pragma unroll
        for (int t = 0; t < 6; ++t) {
            int idx = r8 * 6 + t;
            int r = idx >> 4, v4 = idx & 15;
            int ii = i + r - 1;
            float4 val = make_float4(0.f, 0.f, 0.f, 0.f);
            if (ii >= 0 && ii < 64)
                val = *(const float4*)(xp + ii * 64 + v4 * 4);
            int base = (r * 66 + 1 + v4 * 4) * 33 + cs;
            tile[base]      = val.x;  tile[base + 33]  = val.y;
            tile[base + 66] = val.z;  tile[base + 99]  = val.w;
        }
        if (tid < 192) {
            int ci = tid / 6, rem = tid - ci * 6;
            int ki = rem >> 1, side = rem & 1;
            tile[(ki * 66 + side * 65) * 33 + ci] = 0.f;
        }
    }
    __syncthreads();

    // ---- compute mapping ----
    int ci_l = (lane & 15) | ((wave & 1) << 4);      // 0..31
    int jg   = ((lane >> 4) & 3) | ((wave >> 1) << 2); // 0..7

    float xv[3][10];
    #pragma unroll
    for (int ki = 0; ki < 3; ++ki)
        #pragma unroll
        for (int cc = 0; cc < 10; ++cc)
            xv[ki][cc] = tile[(ki * 66 + jg * 8 + cc) * 33 + ci_l];

    float o[6][8];
    const float* wp = pwt + (g * 32 + ci_l) * 72;
    #pragma unroll
    for (int tt = 0; tt < 6; ++tt) {
        float w[9];
        *(float4*)&w[0] = *(const float4*)(wp + tt * 12);
        *(float4*)&w[4] = *(const float4*)(wp + tt * 12 + 4);
        w[8] = wp[tt * 12 + 8];
        #pragma unroll
        for (int p = 0; p < 8; ++p) o[tt][p] = 0.f;
        #pragma unroll
        for (int ki = 0; ki < 3; ++ki)
            #pragma unroll
            for (int kj = 0; kj < 3; ++kj) {
                float wgt = w[ki * 3 + kj];
                #pragma unroll
                for (int p = 0; p < 8; ++p)
                    o[tt][p] += wgt * xv[ki][kj + p];
            }
    }

    // ---- 16-ci reduce on VALU (DPP): xor1, xor2, ror4, ror8 ----
    #pragma unroll
    for (int tt = 0; tt < 6; ++tt)
        #pragma unroll
        for (int p = 0; p < 8; ++p) {
            float v = o[tt][p];
            v = dpp_add<0xB1>(v);    // quad_perm [1,0,3,2]  : xor1
            v = dpp_add<0x4E>(v);    // quad_perm [2,3,0,1]  : xor2
            v = dpp_add<0x124>(v);   // row_ror:4
            v = dpp_add<0x128>(v);   // row_ror:8  -> full 16-lane row sum
            o[tt][p] = v;
        }

    // ---- cross-wave (ci bit4) combine via small LDS buffer ----
    __syncthreads();                   // x-tile reads done; alias as s2
    if ((lane & 15) == 0) {            // one writer per (wave, jg-group)
        int jgl = (lane >> 4) & 3;
        float* s2 = &tile[wave * 192 + jgl * 48];
        #pragma unroll
        for (int tt = 0; tt < 6; ++tt) {
            *(float4*)&s2[tt * 8]     = make_float4(o[tt][0], o[tt][1], o[tt][2], o[tt][3]);
            *(float4*)&s2[tt * 8 + 4] = make_float4(o[tt][4], o[tt][5], o[tt][6], o[tt][7]);
        }
    }
    __syncthreads();
    size_t pslot = (size_t)bi * 8 + g;
    for (int idx = tid; idx < 384; idx += 256) {
        int tt = idx >> 6, rem = idx & 63;
        int jjg = rem >> 3, p = rem & 7;
        int pr = jjg >> 2, jgl = jjg & 3;
        float s = tile[(pr * 2) * 192 + jgl * 48 + tt * 8 + p]
                + tile[(pr * 2 + 1) * 192 + jgl * 48 + tt * 8 + p];
        part[pslot * 384 + idx] = s;
    }
}

// ---------------- K1b: offset stage 2 -> paired gather tables ---------------
__global__ __launch_bounds__(256) void offset_s2_kernel(
    const float* __restrict__ part, const float* __restrict__ pb,
    int2* __restrict__ tbl_off, float4* __restrict__ tbl_w)
{
    int pix = blockIdx.x * 256 + threadIdx.x;   // grid=128
    int b = pix >> 12, rem = pix & 4095, i = rem >> 6, j = rem & 63;
    int bi = b * 64 + i;
    float v[6];
    #pragma unroll
    for (int tt = 0; tt < 6; ++tt) v[tt] = pb[tt];
    for (int g = 0; g < 8; ++g) {
        const float* pp = part + ((size_t)bi * 8 + g) * 384;
        #pragma unroll
        for (int tt = 0; tt < 6; ++tt) v[tt] += pp[tt * 64 + j];
    }
    const float pnx[3] = {0.f, 0.f, 1.f};
    const float pny[3] = {0.f, 1.f, 0.f};
    #pragma unroll
    for (int n = 0; n < 3; ++n) {
        float px_ = (float)i + pnx[n] + v[n];
        float py_ = (float)j + pny[n] + v[n + 3];
        float qx = floorf(px_), qy = floorf(py_);
        float qlx = fminf(fmaxf(qx,       0.f), 63.f);
        float qly = fminf(fmaxf(qy,       0.f), 63.f);
        float qrx = fminf(fmaxf(qx + 1.f, 0.f), 63.f);
        float qry = fminf(fmaxf(qy + 1.f, 0.f), 63.f);
        float pxc = fminf(fmaxf(px_,      0.f), 63.f);
        float pyc = fminf(fmaxf(py_,      0.f), 63.f);
        float glt = (1.f + (qlx - pxc)) * (1.f + (qly - pyc));
        float grb = (1.f - (qrx - pxc)) * (1.f - (qry - pyc));
        float glb = (1.f + (qlx - pxc)) * (1.f - (qry - pyc));
        float grt = (1.f - (qrx - pxc)) * (1.f + (qly - pyc));
        int ilx = (int)qlx, irx = (int)qrx;
        int ily = (int)qly, iry = (int)qry;
        int c0; float a0, a1, b0, b1;
        if (ily == iry) {
            if (ily == 0) { c0 = 0;  a0 = glt + glb; a1 = 0.f; b0 = grt + grb; b1 = 0.f; }
            else          { c0 = 62; a0 = 0.f; a1 = glt + glb; b0 = 0.f; b1 = grt + grb; }
        } else { c0 = ily; a0 = glt; a1 = glb; b0 = grt; b1 = grb; }
        int oi = (b * 3 + n) * HW_ + i * 64 + j;
        tbl_off[oi] = make_int2(ilx * 64 + c0, irx * 64 + c0);
        tbl_w[oi]   = make_float4(a0, a1, b0, b1);
    }
}

// ---------------- K2a: gather — HWC input, coalesced, XCD-swizzled ----------
__global__ __launch_bounds__(256) void gather_kernel(
    const float* __restrict__ xt, const int2* __restrict__ tbl_off,
    const float4* __restrict__ tbl_w, unsigned short* __restrict__ v)
{
    int blk = blockIdx.x;          // 1536
    int b = blk & 7;
    int rest = blk >> 3;           // 0..191
    int n = rest >> 6, i = rest & 63;
    int bi = b * 64 + i;
    int tid = threadIdx.x;
    int lane = tid & 63, wv = tid >> 6;
    int ci4 = lane * 4;
    const float* xb = xt + (size_t)b * 1048576;

    for (int it0 = 0; it0 < 16; it0 += 4) {
        float4 A[4], Bv[4], Cv[4], Dv[4], w4[4];
        #pragma unroll
        for (int u = 0; u < 4; ++u) {
            int j = wv * 16 + it0 + u;
            int oi = (b * 3 + n) * HW_ + i * 64 + j;
            int2 off = tbl_off[oi];
            w4[u] = tbl_w[oi];
            const float* p0 = xb + (size_t)off.x * 256 + ci4;
            const float* p1 = xb + (size_t)off.y * 256 + ci4;
            A[u]  = *(const float4*)p0;
            Bv[u] = *(const float4*)(p0 + 256);
            Cv[u] = *(const float4*)p1;
            Dv[u] = *(const float4*)(p1 + 256);
        }
        #pragma unroll
        for (int u = 0; u < 4; ++u) {
            int j = wv * 16 + it0 + u;
            int pix = bi * 64 + j;
            union { unsigned short h[4]; uint2 q; } pk;
            pk.h[0] = f2bf(w4[u].x*A[u].x + w4[u].y*Bv[u].x + w4[u].z*Cv[u].x + w4[u].w*Dv[u].x);
            pk.h[1] = f2bf(w4[u].x*A[u].y + w4[u].y*Bv[u].y + w4[u].z*Cv[u].y + w4[u].w*Dv[u].y);
            pk.h[2] = f2bf(w4[u].x*A[u].z + w4[u].y*Bv[u].z + w4[u].z*Cv[u].z + w4[u].w*Dv[u].z);
            pk.h[3] = f2bf(w4[u].x*A[u].w + w4[u].y*Bv[u].w + w4[u].z*Cv[u].w + w4[u].w*Dv[u].w);
            *(uint2*)&v[(size_t)pix * 768 + n * 256 + ci4] = pk.q;
        }
    }
}

// ---------------- K2b: AK GEMM (bf16 MFMA, XCD-swizzled) --------------------
__global__ __launch_bounds__(256) void ak_mfma_kernel(
    const unsigned short* __restrict__ v, const unsigned short* __restrict__ W,
    unsigned short* __restrict__ yh, float* __restrict__ p1, float* __restrict__ p2)
{
    int blk = blockIdx.x;              // 512
    int b = blk & 7, i = blk >> 3;
    int tid = threadIdx.x;
    int wv = tid >> 6, lane = tid & 63;
    int quad = lane >> 4, l15 = lane & 15;
    __shared__ __align__(16) unsigned short sA[8192];
    __shared__ __align__(16) unsigned short sB[2048];
    int pixS = tid & 63, kqS = tid >> 6;
    int pix0 = (b * 64 + i) * 64;

    f32x4 acc[4][4];
    #pragma unroll
    for (int mt = 0; mt < 4; ++mt)
        #pragma unroll
        for (int nt = 0; nt < 4; ++nt) acc[mt][nt] = (f32x4){0.f, 0.f, 0.f, 0.f};

    for (int k0 = 0; k0 < 768; k0 += 32) {
        #pragma unroll
        for (int s = 0; s < 4; ++s) {
            int co = tid;
            *(uint4*)&sA[(s * 256 + co) * 8] =
                *(const uint4*)&W[co * 768 + k0 + s * 8];
        }
        *(uint4*)&sB[(kqS * 64 + pixS) * 8] =
            *(const uint4*)&v[(size_t)(pix0 + pixS) * 768 + k0 + kqS * 8];
        __syncthreads();
        short8 af[4], bf[4];
        #pragma unroll
        for (int mt = 0; mt < 4; ++mt)
            af[mt] = *(const short8*)&sA[(quad * 256 + wv * 64 + mt * 16 + l15) * 8];
        #pragma unroll
        for (int nt = 0; nt < 4; ++nt)
            bf[nt] = *(const short8*)&sB[(quad * 64 + nt * 16 + l15) * 8];
        #pragma unroll
        for (int mt = 0; mt < 4; ++mt)
            #pragma unroll
            for (int nt = 0; nt < 4; ++nt)
                acc[mt][nt] = __builtin_amdgcn_mfma_f32_16x16x32_bf16(
                    af[mt], bf[nt], acc[mt][nt], 0, 0, 0);
        __syncthreads();
    }
    #pragma unroll
    for (int mt = 0; mt < 4; ++mt) {
        #pragma unroll
        for (int r = 0; r < 4; ++r) {
            int co = wv * 64 + mt * 16 + quad * 4 + r;
            size_t base = ((size_t)b * C_ + co) * HW_ + i * 64;
            float s1 = 0.f, s2 = 0.f;
            #pragma unroll
            for (int nt = 0; nt < 4; ++nt) {
                float val = acc[mt][nt][r];
                s1 += val; s2 += val * val;
                yh[base + nt * 16 + l15] = f2bf(val);
            }
            #pragma unroll
            for (int m = 1; m < 16; m <<= 1) {
                s1 += __shfl_xor(s1, m); s2 += __shfl_xor(s2, m);
            }
            if (l15 == 0) { p1[co * 512 + blk] = s1; p2[co * 512 + blk] = s2; }
        }
    }
}

// ---------------- K3: BN stats from partials --------------------------------
__global__ __launch_bounds__(256) void bn_stats_kernel(
    const float* __restrict__ p1, const float* __restrict__ p2,
    const float* __restrict__ gamma, const float* __restrict__ beta,
    float* __restrict__ ss)
{
    int co = blockIdx.x, tid = threadIdx.x;     // grid=256
    float a = p1[co * 512 + tid] + p1[co * 512 + 256 + tid];
    float q = p2[co * 512 + tid] + p2[co * 512 + 256 + tid];
    __shared__ float r1[256], r2[256];
    r1[tid] = a; r2[tid] = q; __syncthreads();
    for (int st = 128; st > 0; st >>= 1) {
        if (tid < st) { r1[tid] += r1[tid + st]; r2[tid] += r2[tid + st]; }
        __syncthreads();
    }
    if (tid == 0) {
        const float inv_n = 1.f / (float)NPIX;
        float m = r1[0] * inv_n;
        float var = r2[0] * inv_n - m * m;
        float sc = gamma[co] * rsqrtf(var + 1e-5f);
        ss[co] = sc; ss[256 + co] = beta[co] - m * sc;
    }
}

// ---------------- K4: fused BN+SiLU + 5x5 depthwise (XCD-swizzled) ----------
__global__ __launch_bounds__(256) void dw5_fused_kernel(
    const unsigned short* __restrict__ in, const float* __restrict__ ss,
    const float* __restrict__ w, const float* __restrict__ bias,
    unsigned short* __restrict__ out)
{
    int blkI = blockIdx.x;         // 2048
    int b = blkI & 7, c = blkI >> 3;
    int bc = b * 256 + c;
    int tid = threadIdx.x;
    __shared__ float tile[68 * 68];
    float sc = ss[c], sh = ss[256 + c];
    const unsigned short* ip = in + (size_t)bc * HW_;
    for (int s = tid; s < 68 * 68; s += 256) {
        int r = s / 68, cc = s - r * 68;
        int ii = r - 2, jj = cc - 2;
        float vv = 0.f;
        if (ii >= 0 && ii < 64 && jj >= 0 && jj < 64) {
            float t = b2f(ip[ii * 64 + jj]) * sc + sh;
            vv = silu_f(t);
        }
        tile[s] = vv;
    }
    float wr[25];
    #pragma unroll
    for (int t = 0; t < 25; ++t) wr[t] = w[c * 25 + t];
    float bv = bias[c];
    __syncthreads();
    int j0 = (tid & 15) * 4, ig = tid >> 4;
    unsigned short* op = out + (size_t)bc * HW_;
    for (int r = 0; r < 4; ++r) {
        int i = r * 16 + ig;
        float o0 = bv, o1 = bv, o2 = bv, o3 = bv;
        #pragma unroll
        for (int di = 0; di < 5; ++di) {
            const float* tp = &tile[(i + di) * 68 + j0];
            float4 a = *(const float4*)tp;
            float4 bq = *(const float4*)(tp + 4);
            float vv[8] = {a.x, a.y, a.z, a.w, bq.x, bq.y, bq.z, bq.w};
            #pragma unroll
            for (int dj = 0; dj < 5; ++dj) {
                float wv = wr[di * 5 + dj];
                o0 += wv * vv[dj];     o1 += wv * vv[dj + 1];
                o2 += wv * vv[dj + 2]; o3 += wv * vv[dj + 3];
            }
        }
        union { unsigned short h[4]; uint2 u; } pk;
        pk.h[0] = f2bf(o0); pk.h[1] = f2bf(o1);
        pk.h[2] = f2bf(o2); pk.h[3] = f2bf(o3);
        *(uint2*)&op[i * 64 + j0] = pk.u;
    }
}

// ---------------- K5: 7x7 dilated(3) depthwise (XCD-swizzled) ---------------
__global__ __launch_bounds__(256) void dw7d3_kernel(
    const unsigned short* __restrict__ in, const float* __restrict__ w,
    const float* __restrict__ bias, unsigned short* __restrict__ out)
{
    int blkI = blockIdx.x;         // 2048
    int b = blkI & 7, c = blkI >> 3;
    int bc = b * 256 + c;
    int tid = threadIdx.x;
    __shared__ float tile[82 * 84];
    const unsigned short* ip = in + (size_t)bc * HW_;
    for (int s = tid; s < 82 * 84; s += 256) {
        int r = s / 84, cc = s - r * 84;
        int ii = r - 9, jj = cc - 9;
        float vv = 0.f;
        if (ii >= 0 && ii < 64 && jj >= 0 && jj < 64) vv = b2f(ip[ii * 64 + jj]);
        tile[s] = vv;
    }
    float wr[49];
    #pragma unroll
    for (int t = 0; t < 49; ++t) wr[t] = w[c * 49 + t];
    float bv = bias[c];
    __syncthreads();
    int j0 = (tid & 15) * 4, ig = tid >> 4;
    unsigned short* op = out + (size_t)bc * HW_;
    for (int r = 0; r < 4; ++r) {
        int i = r * 16 + ig;
        float o0 = bv, o1 = bv, o2 = bv, o3 = bv;
        #pragma unroll
        for (int di = 0; di < 7; ++di) {
            const float* tp = &tile[(i + 3 * di) * 84 + j0];
            float vv[24];
            #pragma unroll
            for (int q = 0; q < 6; ++q)
                *(float4*)&vv[q * 4] = *(const float4*)(tp + q * 4);
            #pragma unroll
            for (int dj = 0; dj < 7; ++dj) {
                float wv = wr[di * 7 + dj];
                o0 += wv * vv[3 * dj];     o1 += wv * vv[3 * dj + 1];
                o2 += wv * vv[3 * dj + 2]; o3 += wv * vv[3 * dj + 3];
            }
        }
        union { unsigned short h[4]; uint2 u; } pk;
        pk.h[0] = f2bf(o0); pk.h[1] = f2bf(o1);
        pk.h[2] = f2bf(o2); pk.h[3] = f2bf(o3);
        *(uint2*)&op[i * 64 + j0] = pk.u;
    }
}

// ---------------- K6/K7: 1x1 conv bf16 MFMA GEMM (XCD-swizzled) -------------
template<int MODE>
__global__ __launch_bounds__(256) void gemm1x1_mfma(
    const unsigned short* __restrict__ in, const unsigned short* __restrict__ W,
    const float* __restrict__ bias,
    const unsigned short* __restrict__ auxh, const float* __restrict__ auxf,
    const float* __restrict__ ss,
    unsigned short* __restrict__ out_bf, float* __restrict__ out_f)
{
    int blk = blockIdx.x;              // 512
    int b = blk & 7, i = blk >> 3;
    int tid = threadIdx.x;
    int wv = tid >> 6, lane = tid & 63;
    int quad = lane >> 4, l15 = lane & 15;
    __shared__ __align__(16) unsigned short sA[8192];
    __shared__ __align__(16) unsigned short sB[2048];
    int pixS = tid & 63, kqS = tid >> 6;

    f32x4 acc[4][4];
    #pragma unroll
    for (int mt = 0; mt < 4; ++mt)
        #pragma unroll
        for (int nt = 0; nt < 4; ++nt) acc[mt][nt] = (f32x4){0.f, 0.f, 0.f, 0.f};

    for (int k0 = 0; k0 < 256; k0 += 32) {
        #pragma unroll
        for (int s = 0; s < 4; ++s) {
            int co = tid;
            *(uint4*)&sA[(s * 256 + co) * 8] =
                *(const uint4*)&W[co * 256 + k0 + s * 8];
        }
        {
            const unsigned short* vp =
                in + ((size_t)b * C_ + k0 + kqS * 8) * HW_ + i * 64 + pixS;
            union { unsigned short h[8]; uint4 u; } hb;
            #pragma unroll
            for (int jj = 0; jj < 8; ++jj) hb.h[jj] = vp[(size_t)jj * HW_];
            *(uint4*)&sB[(kqS * 64 + pixS) * 8] = hb.u;
        }
        __syncthreads();
        short8 af[4], bf[4];
        #pragma unroll
        for (int mt = 0; mt < 4; ++mt)
            af[mt] = *(const short8*)&sA[(quad * 256 + wv * 64 + mt * 16 + l15) * 8];
        #pragma unroll
        for (int nt = 0; nt < 4; ++nt)
            bf[nt] = *(const short8*)&sB[(quad * 64 + nt * 16 + l15) * 8];
        #pragma unroll
        for (int mt = 0; mt < 4; ++mt)
            #pragma unroll
            for (int nt = 0; nt < 4; ++nt)
                acc[mt][nt] = __builtin_amdgcn_mfma_f32_16x16x32_bf16(
                    af[mt], bf[nt], acc[mt][nt], 0, 0, 0);
        __syncthreads();
    }
    #pragma unroll
    for (int mt = 0; mt < 4; ++mt) {
        #pragma unroll
        for (int r = 0; r < 4; ++r) {
            int co = wv * 64 + mt * 16 + quad * 4 + r;
            float bco = bias[co];
            size_t base = ((size_t)b * C_ + co) * HW_ + i * 64;
            if (MODE == 0) {
                float sc = ss[co], sh = ss[256 + co];
                #pragma unroll
                for (int nt = 0; nt < 4; ++nt) {
                    int col = nt * 16 + l15;
                    float o = acc[mt][nt][r] + bco;
                    float u = silu_f(b2f(auxh[base + col]) * sc + sh);
                    out_bf[base + col] = f2bf(o * u);
                }
            } else {
                #pragma unroll
                for (int nt = 0; nt < 4; ++nt) {
                    int col = nt * 16 + l15;
                    out_f[base + col] = acc[mt][nt][r] + bco + auxf[base + col];
                }
            }
        }
    }
}

// ---------------- launch ----------------------------------------------------
extern "C" void kernel_launch(void* const* d_in, const int* in_sizes, int n_in,
                              void* d_out, int out_size, void* d_ws, size_t ws_size,
                              hipStream_t stream) {
    const float* x     = (const float*)d_in[0];
    const float* p_w   = (const float*)d_in[1];
    const float* p_b   = (const float*)d_in[2];
    const float* ak_w  = (const float*)d_in[3];
    const float* ak_g  = (const float*)d_in[4];
    const float* ak_b  = (const float*)d_in[5];
    const float* l0_w  = (const float*)d_in[6];
    const float* l0_b  = (const float*)d_in[7];
    const float* ls_w  = (const float*)d_in[8];
    const float* ls_b  = (const float*)d_in[9];
    const float* l1_w  = (const float*)d_in[10];
    const float* l1_b  = (const float*)d_in[11];
    const float* cv_w  = (const float*)d_in[12];
    const float* cv_b  = (const float*)d_in[13];
    float* out = (float*)d_out;

    char* w = (char*)d_ws;
    int2*   tbl_off = (int2*)w;                              // 786 KB
    float4* tbl_w   = (float4*)(w + 786432);                 // 1.5 MB
    unsigned short* wak = (unsigned short*)(w + 2359296);    // 384 KB
    unsigned short* wl1 = (unsigned short*)(w + 2752512);    // 128 KB
    unsigned short* wcv = (unsigned short*)(w + 2883584);    // 128 KB
    float* p1 = (float*)(w + 3014656);                       // 512 KB
    float* p2 = (float*)(w + 3538944);                       // 512 KB
    float* ss = (float*)(w + 4063232);                       // 2 KB
    float* pwt = (float*)(w + 4065280);                      // 72 KB
    // time-multiplexed regions:
    float* xt   = (float*)(w + 4194304);                     // 32 MB (dead after gather)
    unsigned short* ybh    = (unsigned short*)(w + 4194304); // 16 MB (ak writes, after gather)
    unsigned short* dw5out = (unsigned short*)(w + 20971520);// 16 MB
    float* part = (float*)(w + 37748736);                    // 6.3 MB (dead after s2)
    unsigned short* attn   = (unsigned short*)(w + 37748736);// 16 MB (dw7 out)
    unsigned short* v      = (unsigned short*)(w + 44040192);// 48 MB (dead after ak)
    unsigned short* g0out  = (unsigned short*)(w + 54525952);// 16 MB (after gemm0)

    prep_kernel<<<1352, 256, 0, stream>>>(ak_w, l1_w, cv_w, p_w, wak, wl1, wcv, pwt);
    offset_s1_kernel<<<4096, 256, 0, stream>>>(x, pwt, part);
    offset_s2_kernel<<<128, 256, 0, stream>>>(part, p_b, tbl_off, tbl_w);
    transpose_kernel<<<1024, 256, 0, stream>>>(x, xt);
    gather_kernel<<<1536, 256, 0, stream>>>(xt, tbl_off, tbl_w, v);
    ak_mfma_kernel<<<512, 256, 0, stream>>>(v, wak, ybh, p1, p2);
    bn_stats_kernel<<<256, 256, 0, stream>>>(p1, p2, ak_g, ak_b, ss);
    dw5_fused_kernel<<<2048, 256, 0, stream>>>(ybh, ss, l0_w, l0_b, dw5out);
    dw7d3_kernel<<<2048, 256, 0, stream>>>(dw5out, ls_w, ls_b, attn);
    gemm1x1_mfma<0><<<512, 256, 0, stream>>>(attn, wl1, l1_b, ybh, nullptr, ss, g0out, nullptr);
    gemm1x1_mfma<1><<<512, 256, 0, stream>>>(g0out, wcv, cv_b, nullptr, x, nullptr, nullptr, out);
}

// Round 10
// 317.888 us; speedup vs baseline: 1.0165x; 1.0165x over previous
//
#include <hip/hip_runtime.h>
#include <math.h>
#include <stdint.h>

#define B_ 8
#define C_ 256
#define HW_ 4096
#define NPIX 32768
#define NELEM (B_*C_*HW_)   // 8388608

typedef __attribute__((ext_vector_type(8))) short short8;
typedef __attribute__((ext_vector_type(4))) float f32x4;

__device__ __forceinline__ unsigned short f2bf(float f) {
    union { float f; uint32_t u; } v; v.f = f;
    uint32_t r = v.u + 0x7FFFu + ((v.u >> 16) & 1u);
    return (unsigned short)(r >> 16);
}
__device__ __forceinline__ float b2f(unsigned short h) {
    union { uint32_t u; float f; } v; v.u = ((uint32_t)h) << 16; return v.f;
}
__device__ __forceinline__ float silu_f(float v) { return v / (1.f + __expf(-v)); }

// ---------------- K0: weight conversion + p_w transpose ---------------------
__global__ __launch_bounds__(256) void prep_kernel(
    const float* __restrict__ akw, const float* __restrict__ l1w,
    const float* __restrict__ cvw, const float* __restrict__ pw,
    unsigned short* __restrict__ wak, unsigned short* __restrict__ wl1,
    unsigned short* __restrict__ wcv, float* __restrict__ pwt)
{
    int gid = blockIdx.x * 256 + threadIdx.x;      // grid=1352
    if (gid < 196608) {
        unsigned co = (unsigned)gid / 768u;
        unsigned kp = (unsigned)gid - co * 768u;   // k'' = n*256+ci
        unsigned n = kp >> 8, ci = kp & 255;
        wak[gid] = f2bf(akw[co * 768 + ci * 3 + n]);
    }
    else if (gid < 262144) { int g = gid - 196608; wl1[g] = f2bf(l1w[g]); }
    else if (gid < 327680) { int g = gid - 262144; wcv[g] = f2bf(cvw[g]); }
    else if (gid < 346112) {
        int idx = gid - 327680;
        int ci = idx / 72, r = idx - ci * 72;
        int tt = r / 12, t9 = r - tt * 12;
        pwt[idx] = (t9 < 9) ? pw[tt * 2304 + ci * 9 + t9] : 0.f;
    }
}

// ---------------- K0b: x CHW -> HWC transpose (XCD-swizzled) ----------------
__global__ __launch_bounds__(256) void transpose_kernel(
    const float* __restrict__ x, float* __restrict__ xt)
{
    int blk = blockIdx.x;            // 1024
    int b = blk & 7;
    int rest = blk >> 3;             // 0..127
    int half = rest & 1, i = rest >> 1;
    int bi = b * 64 + i;
    int tid = threadIdx.x;
    __shared__ float tile[64 * 132];

    {
        int ci_l = tid >> 6, jj = tid & 63;
        const float* ip = x + ((size_t)b * C_ + half * 128 + ci_l) * HW_ + i * 64 + jj;
        #pragma unroll 4
        for (int it = 0; it < 32; ++it)
            tile[jj * 132 + ci_l + it * 4] = ip[(size_t)it * 4 * HW_];
    }
    __syncthreads();
    {
        int j = tid >> 2, q = tid & 3;
        float* op = xt + ((size_t)(bi * 64 + j)) * 256 + half * 128 + q * 32;
        #pragma unroll
        for (int f = 0; f < 8; ++f)
            *(float4*)(op + f * 4) = *(const float4*)&tile[j * 132 + q * 32 + f * 4];
    }
}

// ---------------- K1a: offset conv stage 1 (v5: register acc, small tree) ---
// Threads: sub = tid>>4 (16 ci-subs), jq = tid&15 (4 pixels each).
// Each thread: 2 serial ci (ci = sub + 16t), acc[6][4] in registers.
// Reduction: single 16-way LDS tree over 384 outputs (no shuffles/DPP).
__global__ __launch_bounds__(256) void offset_s1_kernel(
    const float* __restrict__ x, const float* __restrict__ pwt,
    float* __restrict__ part)          // [bi*8+g][6][64]
{
    int blk = blockIdx.x;              // 4096
    int b = blk & 7;
    int rest = blk >> 3;               // 0..511
    int g = rest & 7, i = rest >> 3;
    int bi = b * 64 + i;
    int tid = threadIdx.x;

    __shared__ float tile[6600];       // x tile [(row*66+col)*33+ci]; aliased as s2[16][387]

    // ---- stage x tile (transposed, halo-padded) ----
    {
        int cs = tid >> 3, r8 = tid & 7;
        const float* xp = x + ((size_t)b * C_ + g * 32 + cs) * HW_;
        #pragma unroll
        for (int t = 0; t < 6; ++t) {
            int idx = r8 * 6 + t;
            int r = idx >> 4, v4 = idx & 15;
            int ii = i + r - 1;
            float4 val = make_float4(0.f, 0.f, 0.f, 0.f);
            if (ii >= 0 && ii < 64)
                val = *(const float4*)(xp + ii * 64 + v4 * 4);
            int base = (r * 66 + 1 + v4 * 4) * 33 + cs;
            tile[base]      = val.x;  tile[base + 33]  = val.y;
            tile[base + 66] = val.z;  tile[base + 99]  = val.w;
        }
        if (tid < 192) {
            int ci = tid / 6, rem = tid - ci * 6;
            int ki = rem >> 1, side = rem & 1;
            tile[(ki * 66 + side * 65) * 33 + ci] = 0.f;
        }
    }
    __syncthreads();

    int sub = tid >> 4;                // 0..15
    int jq  = tid & 15;                // 0..15: pixels jq*4 .. jq*4+3

    float acc[6][4];
    #pragma unroll
    for (int tt = 0; tt < 6; ++tt)
        #pragma unroll
        for (int p = 0; p < 4; ++p) acc[tt][p] = 0.f;

    #pragma unroll
    for (int t = 0; t < 2; ++t) {
        int ci = sub + 16 * t;
        float xv[3][6];                // tile cols jq*4 .. jq*4+5
        #pragma unroll
        for (int ki = 0; ki < 3; ++ki)
            #pragma unroll
            for (int cc = 0; cc < 6; ++cc)
                xv[ki][cc] = tile[(ki * 66 + jq * 4 + cc) * 33 + ci];
        const float* wp = pwt + (g * 32 + ci) * 72;
        #pragma unroll
        for (int tt = 0; tt < 6; ++tt) {
            float w[9];
            *(float4*)&w[0] = *(const float4*)(wp + tt * 12);
            *(float4*)&w[4] = *(const float4*)(wp + tt * 12 + 4);
            w[8] = wp[tt * 12 + 8];
            #pragma unroll
            for (int ki = 0; ki < 3; ++ki)
                #pragma unroll
                for (int kj = 0; kj < 3; ++kj) {
                    float wgt = w[ki * 3 + kj];
                    #pragma unroll
                    for (int p = 0; p < 4; ++p)
                        acc[tt][p] += wgt * xv[ki][kj + p];
                }
        }
    }

    // ---- 16-sub reduction via LDS tree (alias tile as s2, stride 387) ----
    __syncthreads();
    {
        float* s2 = tile + sub * 387;
        #pragma unroll
        for (int tt = 0; tt < 6; ++tt)
            #pragma unroll
            for (int p = 0; p < 4; ++p)
                s2[tt * 64 + jq * 4 + p] = acc[tt][p];
    }
    __syncthreads();
    size_t pslot = (size_t)bi * 8 + g;
    for (int idx = tid; idx < 384; idx += 256) {
        float s = 0.f;
        #pragma unroll
        for (int sb = 0; sb < 16; ++sb)
            s += tile[sb * 387 + idx];
        part[pslot * 384 + idx] = s;
    }
}

// ---------------- K1b: offset stage 2 -> paired gather tables ---------------
__global__ __launch_bounds__(256) void offset_s2_kernel(
    const float* __restrict__ part, const float* __restrict__ pb,
    int2* __restrict__ tbl_off, float4* __restrict__ tbl_w)
{
    int pix = blockIdx.x * 256 + threadIdx.x;   // grid=128
    int b = pix >> 12, rem = pix & 4095, i = rem >> 6, j = rem & 63;
    int bi = b * 64 + i;
    float v[6];
    #pragma unroll
    for (int tt = 0; tt < 6; ++tt) v[tt] = pb[tt];
    for (int g = 0; g < 8; ++g) {
        const float* pp = part + ((size_t)bi * 8 + g) * 384;
        #pragma unroll
        for (int tt = 0; tt < 6; ++tt) v[tt] += pp[tt * 64 + j];
    }
    const float pnx[3] = {0.f, 0.f, 1.f};
    const float pny[3] = {0.f, 1.f, 0.f};
    #pragma unroll
    for (int n = 0; n < 3; ++n) {
        float px_ = (float)i + pnx[n] + v[n];
        float py_ = (float)j + pny[n] + v[n + 3];
        float qx = floorf(px_), qy = floorf(py_);
        float qlx = fminf(fmaxf(qx,       0.f), 63.f);
        float qly = fminf(fmaxf(qy,       0.f), 63.f);
        float qrx = fminf(fmaxf(qx + 1.f, 0.f), 63.f);
        float qry = fminf(fmaxf(qy + 1.f, 0.f), 63.f);
        float pxc = fminf(fmaxf(px_,      0.f), 63.f);
        float pyc = fminf(fmaxf(py_,      0.f), 63.f);
        float glt = (1.f + (qlx - pxc)) * (1.f + (qly - pyc));
        float grb = (1.f - (qrx - pxc)) * (1.f - (qry - pyc));
        float glb = (1.f + (qlx - pxc)) * (1.f - (qry - pyc));
        float grt = (1.f - (qrx - pxc)) * (1.f + (qly - pyc));
        int ilx = (int)qlx, irx = (int)qrx;
        int ily = (int)qly, iry = (int)qry;
        int c0; float a0, a1, b0, b1;
        if (ily == iry) {
            if (ily == 0) { c0 = 0;  a0 = glt + glb; a1 = 0.f; b0 = grt + grb; b1 = 0.f; }
            else          { c0 = 62; a0 = 0.f; a1 = glt + glb; b0 = 0.f; b1 = grt + grb; }
        } else { c0 = ily; a0 = glt; a1 = glb; b0 = grt; b1 = grb; }
        int oi = (b * 3 + n) * HW_ + i * 64 + j;
        tbl_off[oi] = make_int2(ilx * 64 + c0, irx * 64 + c0);
        tbl_w[oi]   = make_float4(a0, a1, b0, b1);
    }
}

// ---------------- K2a: gather — HWC input, coalesced, XCD-swizzled ----------
__global__ __launch_bounds__(256) void gather_kernel(
    const float* __restrict__ xt, const int2* __restrict__ tbl_off,
    const float4* __restrict__ tbl_w, unsigned short* __restrict__ v)
{
    int blk = blockIdx.x;          // 1536
    int b = blk & 7;
    int rest = blk >> 3;           // 0..191
    int n = rest >> 6, i = rest & 63;
    int bi = b * 64 + i;
    int tid = threadIdx.x;
    int lane = tid & 63, wv = tid >> 6;
    int ci4 = lane * 4;
    const float* xb = xt + (size_t)b * 1048576;

    for (int it0 = 0; it0 < 16; it0 += 4) {
        float4 A[4], Bv[4], Cv[4], Dv[4], w4[4];
        #pragma unroll
        for (int u = 0; u < 4; ++u) {
            int j = wv * 16 + it0 + u;
            int oi = (b * 3 + n) * HW_ + i * 64 + j;
            int2 off = tbl_off[oi];
            w4[u] = tbl_w[oi];
            const float* p0 = xb + (size_t)off.x * 256 + ci4;
            const float* p1 = xb + (size_t)off.y * 256 + ci4;
            A[u]  = *(const float4*)p0;
            Bv[u] = *(const float4*)(p0 + 256);
            Cv[u] = *(const float4*)p1;
            Dv[u] = *(const float4*)(p1 + 256);
        }
        #pragma unroll
        for (int u = 0; u < 4; ++u) {
            int j = wv * 16 + it0 + u;
            int pix = bi * 64 + j;
            union { unsigned short h[4]; uint2 q; } pk;
            pk.h[0] = f2bf(w4[u].x*A[u].x + w4[u].y*Bv[u].x + w4[u].z*Cv[u].x + w4[u].w*Dv[u].x);
            pk.h[1] = f2bf(w4[u].x*A[u].y + w4[u].y*Bv[u].y + w4[u].z*Cv[u].y + w4[u].w*Dv[u].y);
            pk.h[2] = f2bf(w4[u].x*A[u].z + w4[u].y*Bv[u].z + w4[u].z*Cv[u].z + w4[u].w*Dv[u].z);
            pk.h[3] = f2bf(w4[u].x*A[u].w + w4[u].y*Bv[u].w + w4[u].z*Cv[u].w + w4[u].w*Dv[u].w);
            *(uint2*)&v[(size_t)pix * 768 + n * 256 + ci4] = pk.q;
        }
    }
}

// ---------------- K2b: AK GEMM (bf16 MFMA, XCD-swizzled) --------------------
__global__ __launch_bounds__(256) void ak_mfma_kernel(
    const unsigned short* __restrict__ v, const unsigned short* __restrict__ W,
    unsigned short* __restrict__ yh, float* __restrict__ p1, float* __restrict__ p2)
{
    int blk = blockIdx.x;              // 512
    int b = blk & 7, i = blk >> 3;
    int tid = threadIdx.x;
    int wv = tid >> 6, lane = tid & 63;
    int quad = lane >> 4, l15 = lane & 15;
    __shared__ __align__(16) unsigned short sA[8192];
    __shared__ __align__(16) unsigned short sB[2048];
    int pixS = tid & 63, kqS = tid >> 6;
    int pix0 = (b * 64 + i) * 64;

    f32x4 acc[4][4];
    #pragma unroll
    for (int mt = 0; mt < 4; ++mt)
        #pragma unroll
        for (int nt = 0; nt < 4; ++nt) acc[mt][nt] = (f32x4){0.f, 0.f, 0.f, 0.f};

    for (int k0 = 0; k0 < 768; k0 += 32) {
        #pragma unroll
        for (int s = 0; s < 4; ++s) {
            int co = tid;
            *(uint4*)&sA[(s * 256 + co) * 8] =
                *(const uint4*)&W[co * 768 + k0 + s * 8];
        }
        *(uint4*)&sB[(kqS * 64 + pixS) * 8] =
            *(const uint4*)&v[(size_t)(pix0 + pixS) * 768 + k0 + kqS * 8];
        __syncthreads();
        short8 af[4], bf[4];
        #pragma unroll
        for (int mt = 0; mt < 4; ++mt)
            af[mt] = *(const short8*)&sA[(quad * 256 + wv * 64 + mt * 16 + l15) * 8];
        #pragma unroll
        for (int nt = 0; nt < 4; ++nt)
            bf[nt] = *(const short8*)&sB[(quad * 64 + nt * 16 + l15) * 8];
        #pragma unroll
        for (int mt = 0; mt < 4; ++mt)
            #pragma unroll
            for (int nt = 0; nt < 4; ++nt)
                acc[mt][nt] = __builtin_amdgcn_mfma_f32_16x16x32_bf16(
                    af[mt], bf[nt], acc[mt][nt], 0, 0, 0);
        __syncthreads();
    }
    #pragma unroll
    for (int mt = 0; mt < 4; ++mt) {
        #pragma unroll
        for (int r = 0; r < 4; ++r) {
            int co = wv * 64 + mt * 16 + quad * 4 + r;
            size_t base = ((size_t)b * C_ + co) * HW_ + i * 64;
            float s1 = 0.f, s2 = 0.f;
            #pragma unroll
            for (int nt = 0; nt < 4; ++nt) {
                float val = acc[mt][nt][r];
                s1 += val; s2 += val * val;
                yh[base + nt * 16 + l15] = f2bf(val);
            }
            #pragma unroll
            for (int m = 1; m < 16; m <<= 1) {
                s1 += __shfl_xor(s1, m); s2 += __shfl_xor(s2, m);
            }
            if (l15 == 0) { p1[co * 512 + blk] = s1; p2[co * 512 + blk] = s2; }
        }
    }
}

// ---------------- K3: BN stats from partials --------------------------------
__global__ __launch_bounds__(256) void bn_stats_kernel(
    const float* __restrict__ p1, const float* __restrict__ p2,
    const float* __restrict__ gamma, const float* __restrict__ beta,
    float* __restrict__ ss)
{
    int co = blockIdx.x, tid = threadIdx.x;     // grid=256
    float a = p1[co * 512 + tid] + p1[co * 512 + 256 + tid];
    float q = p2[co * 512 + tid] + p2[co * 512 + 256 + tid];
    __shared__ float r1[256], r2[256];
    r1[tid] = a; r2[tid] = q; __syncthreads();
    for (int st = 128; st > 0; st >>= 1) {
        if (tid < st) { r1[tid] += r1[tid + st]; r2[tid] += r2[tid + st]; }
        __syncthreads();
    }
    if (tid == 0) {
        const float inv_n = 1.f / (float)NPIX;
        float m = r1[0] * inv_n;
        float var = r2[0] * inv_n - m * m;
        float sc = gamma[co] * rsqrtf(var + 1e-5f);
        ss[co] = sc; ss[256 + co] = beta[co] - m * sc;
    }
}

// ---------------- K4: fused BN+SiLU + 5x5 depthwise (XCD-swizzled) ----------
__global__ __launch_bounds__(256) void dw5_fused_kernel(
    const unsigned short* __restrict__ in, const float* __restrict__ ss,
    const float* __restrict__ w, const float* __restrict__ bias,
    unsigned short* __restrict__ out)
{
    int blkI = blockIdx.x;         // 2048
    int b = blkI & 7, c = blkI >> 3;
    int bc = b * 256 + c;
    int tid = threadIdx.x;
    __shared__ float tile[68 * 68];
    float sc = ss[c], sh = ss[256 + c];
    const unsigned short* ip = in + (size_t)bc * HW_;
    for (int s = tid; s < 68 * 68; s += 256) {
        int r = s / 68, cc = s - r * 68;
        int ii = r - 2, jj = cc - 2;
        float vv = 0.f;
        if (ii >= 0 && ii < 64 && jj >= 0 && jj < 64) {
            float t = b2f(ip[ii * 64 + jj]) * sc + sh;
            vv = silu_f(t);
        }
        tile[s] = vv;
    }
    float wr[25];
    #pragma unroll
    for (int t = 0; t < 25; ++t) wr[t] = w[c * 25 + t];
    float bv = bias[c];
    __syncthreads();
    int j0 = (tid & 15) * 4, ig = tid >> 4;
    unsigned short* op = out + (size_t)bc * HW_;
    for (int r = 0; r < 4; ++r) {
        int i = r * 16 + ig;
        float o0 = bv, o1 = bv, o2 = bv, o3 = bv;
        #pragma unroll
        for (int di = 0; di < 5; ++di) {
            const float* tp = &tile[(i + di) * 68 + j0];
            float4 a = *(const float4*)tp;
            float4 bq = *(const float4*)(tp + 4);
            float vv[8] = {a.x, a.y, a.z, a.w, bq.x, bq.y, bq.z, bq.w};
            #pragma unroll
            for (int dj = 0; dj < 5; ++dj) {
                float wv = wr[di * 5 + dj];
                o0 += wv * vv[dj];     o1 += wv * vv[dj + 1];
                o2 += wv * vv[dj + 2]; o3 += wv * vv[dj + 3];
            }
        }
        union { unsigned short h[4]; uint2 u; } pk;
        pk.h[0] = f2bf(o0); pk.h[1] = f2bf(o1);
        pk.h[2] = f2bf(o2); pk.h[3] = f2bf(o3);
        *(uint2*)&op[i * 64 + j0] = pk.u;
    }
}

// ---------------- K5: 7x7 dilated(3) depthwise (XCD-swizzled) ---------------
__global__ __launch_bounds__(256) void dw7d3_kernel(
    const unsigned short* __restrict__ in, const float* __restrict__ w,
    const float* __restrict__ bias, unsigned short* __restrict__ out)
{
    int blkI = blockIdx.x;         // 2048
    int b = blkI & 7, c = blkI >> 3;
    int bc = b * 256 + c;
    int tid = threadIdx.x;
    __shared__ float tile[82 * 84];
    const unsigned short* ip = in + (size_t)bc * HW_;
    for (int s = tid; s < 82 * 84; s += 256) {
        int r = s / 84, cc = s - r * 84;
        int ii = r - 9, jj = cc - 9;
        float vv = 0.f;
        if (ii >= 0 && ii < 64 && jj >= 0 && jj < 64) vv = b2f(ip[ii * 64 + jj]);
        tile[s] = vv;
    }
    float wr[49];
    #pragma unroll
    for (int t = 0; t < 49; ++t) wr[t] = w[c * 49 + t];
    float bv = bias[c];
    __syncthreads();
    int j0 = (tid & 15) * 4, ig = tid >> 4;
    unsigned short* op = out + (size_t)bc * HW_;
    for (int r = 0; r < 4; ++r) {
        int i = r * 16 + ig;
        float o0 = bv, o1 = bv, o2 = bv, o3 = bv;
        #pragma unroll
        for (int di = 0; di < 7; ++di) {
            const float* tp = &tile[(i + 3 * di) * 84 + j0];
            float vv[24];
            #pragma unroll
            for (int q = 0; q < 6; ++q)
                *(float4*)&vv[q * 4] = *(const float4*)(tp + q * 4);
            #pragma unroll
            for (int dj = 0; dj < 7; ++dj) {
                float wv = wr[di * 7 + dj];
                o0 += wv * vv[3 * dj];     o1 += wv * vv[3 * dj + 1];
                o2 += wv * vv[3 * dj + 2]; o3 += wv * vv[3 * dj + 3];
            }
        }
        union { unsigned short h[4]; uint2 u; } pk;
        pk.h[0] = f2bf(o0); pk.h[1] = f2bf(o1);
        pk.h[2] = f2bf(o2); pk.h[3] = f2bf(o3);
        *(uint2*)&op[i * 64 + j0] = pk.u;
    }
}

// ---------------- K6/K7: 1x1 conv bf16 MFMA GEMM (XCD-swizzled) -------------
template<int MODE>
__global__ __launch_bounds__(256) void gemm1x1_mfma(
    const unsigned short* __restrict__ in, const unsigned short* __restrict__ W,
    const float* __restrict__ bias,
    const unsigned short* __restrict__ auxh, const float* __restrict__ auxf,
    const float* __restrict__ ss,
    unsigned short* __restrict__ out_bf, float* __restrict__ out_f)
{
    int blk = blockIdx.x;              // 512
    int b = blk & 7, i = blk >> 3;
    int tid = threadIdx.x;
    int wv = tid >> 6, lane = tid & 63;
    int quad = lane >> 4, l15 = lane & 15;
    __shared__ __align__(16) unsigned short sA[8192];
    __shared__ __align__(16) unsigned short sB[2048];
    int pixS = tid & 63, kqS = tid >> 6;

    f32x4 acc[4][4];
    #pragma unroll
    for (int mt = 0; mt < 4; ++mt)
        #pragma unroll
        for (int nt = 0; nt < 4; ++nt) acc[mt][nt] = (f32x4){0.f, 0.f, 0.f, 0.f};

    for (int k0 = 0; k0 < 256; k0 += 32) {
        #pragma unroll
        for (int s = 0; s < 4; ++s) {
            int co = tid;
            *(uint4*)&sA[(s * 256 + co) * 8] =
                *(const uint4*)&W[co * 256 + k0 + s * 8];
        }
        {
            const unsigned short* vp =
                in + ((size_t)b * C_ + k0 + kqS * 8) * HW_ + i * 64 + pixS;
            union { unsigned short h[8]; uint4 u; } hb;
            #pragma unroll
            for (int jj = 0; jj < 8; ++jj) hb.h[jj] = vp[(size_t)jj * HW_];
            *(uint4*)&sB[(kqS * 64 + pixS) * 8] = hb.u;
        }
        __syncthreads();
        short8 af[4], bf[4];
        #pragma unroll
        for (int mt = 0; mt < 4; ++mt)
            af[mt] = *(const short8*)&sA[(quad * 256 + wv * 64 + mt * 16 + l15) * 8];
        #pragma unroll
        for (int nt = 0; nt < 4; ++nt)
            bf[nt] = *(const short8*)&sB[(quad * 64 + nt * 16 + l15) * 8];
        #pragma unroll
        for (int mt = 0; mt < 4; ++mt)
            #pragma unroll
            for (int nt = 0; nt < 4; ++nt)
                acc[mt][nt] = __builtin_amdgcn_mfma_f32_16x16x32_bf16(
                    af[mt], bf[nt], acc[mt][nt], 0, 0, 0);
        __syncthreads();
    }
    #pragma unroll
    for (int mt = 0; mt < 4; ++mt) {
        #pragma unroll
        for (int r = 0; r < 4; ++r) {
            int co = wv * 64 + mt * 16 + quad * 4 + r;
            float bco = bias[co];
            size_t base = ((size_t)b * C_ + co) * HW_ + i * 64;
            if (MODE == 0) {
                float sc = ss[co], sh = ss[256 + co];
                #pragma unroll
                for (int nt = 0; nt < 4; ++nt) {
                    int col = nt * 16 + l15;
                    float o = acc[mt][nt][r] + bco;
                    float u = silu_f(b2f(auxh[base + col]) * sc + sh);
                    out_bf[base + col] = f2bf(o * u);
                }
            } else {
                #pragma unroll
                for (int nt = 0; nt < 4; ++nt) {
                    int col = nt * 16 + l15;
                    out_f[base + col] = acc[mt][nt][r] + bco + auxf[base + col];
                }
            }
        }
    }
}

// ---------------- launch ----------------------------------------------------
extern "C" void kernel_launch(void* const* d_in, const int* in_sizes, int n_in,
                              void* d_out, int out_size, void* d_ws, size_t ws_size,
                              hipStream_t stream) {
    const float* x     = (const float*)d_in[0];
    const float* p_w   = (const float*)d_in[1];
    const float* p_b   = (const float*)d_in[2];
    const float* ak_w  = (const float*)d_in[3];
    const float* ak_g  = (const float*)d_in[4];
    const float* ak_b  = (const float*)d_in[5];
    const float* l0_w  = (const float*)d_in[6];
    const float* l0_b  = (const float*)d_in[7];
    const float* ls_w  = (const float*)d_in[8];
    const float* ls_b  = (const float*)d_in[9];
    const float* l1_w  = (const float*)d_in[10];
    const float* l1_b  = (const float*)d_in[11];
    const float* cv_w  = (const float*)d_in[12];
    const float* cv_b  = (const float*)d_in[13];
    float* out = (float*)d_out;

    char* w = (char*)d_ws;
    int2*   tbl_off = (int2*)w;                              // 786 KB
    float4* tbl_w   = (float4*)(w + 786432);                 // 1.5 MB
    unsigned short* wak = (unsigned short*)(w + 2359296);    // 384 KB
    unsigned short* wl1 = (unsigned short*)(w + 2752512);    // 128 KB
    unsigned short* wcv = (unsigned short*)(w + 2883584);    // 128 KB
    float* p1 = (float*)(w + 3014656);                       // 512 KB
    float* p2 = (float*)(w + 3538944);                       // 512 KB
    float* ss = (float*)(w + 4063232);                       // 2 KB
    float* pwt = (float*)(w + 4065280);                      // 72 KB
    // time-multiplexed regions:
    float* xt   = (float*)(w + 4194304);                     // 32 MB (dead after gather)
    unsigned short* ybh    = (unsigned short*)(w + 4194304); // 16 MB (ak writes, after gather)
    unsigned short* dw5out = (unsigned short*)(w + 20971520);// 16 MB
    float* part = (float*)(w + 37748736);                    // 6.3 MB (dead after s2)
    unsigned short* attn   = (unsigned short*)(w + 37748736);// 16 MB (dw7 out)
    unsigned short* v      = (unsigned short*)(w + 44040192);// 48 MB (dead after ak)
    unsigned short* g0out  = (unsigned short*)(w + 54525952);// 16 MB (after gemm0)

    prep_kernel<<<1352, 256, 0, stream>>>(ak_w, l1_w, cv_w, p_w, wak, wl1, wcv, pwt);
    offset_s1_kernel<<<4096, 256, 0, stream>>>(x, pwt, part);
    offset_s2_kernel<<<128, 256, 0, stream>>>(part, p_b, tbl_off, tbl_w);
    transpose_kernel<<<1024, 256, 0, stream>>>(x, xt);
    gather_kernel<<<1536, 256, 0, stream>>>(xt, tbl_off, tbl_w, v);
    ak_mfma_kernel<<<512, 256, 0, stream>>>(v, wak, ybh, p1, p2);
    bn_stats_kernel<<<256, 256, 0, stream>>>(p1, p2, ak_g, ak_b, ss);
    dw5_fused_kernel<<<2048, 256, 0, stream>>>(ybh, ss, l0_w, l0_b, dw5out);
    dw7d3_kernel<<<2048, 256, 0, stream>>>(dw5out, ls_w, ls_b, attn);
    gemm1x1_mfma<0><<<512, 256, 0, stream>>>(attn, wl1, l1_b, ybh, nullptr, ss, g0out, nullptr);
    gemm1x1_mfma<1><<<512, 256, 0, stream>>>(g0out, wcv, cv_b, nullptr, x, nullptr, nullptr, out);
}